// Round 3
// baseline (384953.833 us; speedup 1.0000x reference)
//
#include <hip/hip_runtime.h>
#include <hip/hip_fp16.h>
#include <math.h>

#define NWG 256        // persistent workgroups (== CU count)
#define SPIN_MAX (1<<13)

__device__ __forceinline__ float dot4(const float4 a, const float4 b) {
  return a.x*b.x + a.y*b.y + a.z*b.z + a.w*b.w;
}
__device__ __forceinline__ float sigm(float v) { return 1.f/(1.f + expf(-v)); }

__device__ __forceinline__ float4 ld4(const float* p) { return *(const float4*)p; }
__device__ __forceinline__ float4 ld4(const __half* p) {
  uint2 r = *(const uint2*)p;
  __half2 h0 = *reinterpret_cast<__half2*>(&r.x);
  __half2 h1 = *reinterpret_cast<__half2*>(&r.y);
  float2 f0 = __half22float2(h0), f1 = __half22float2(h1);
  return make_float4(f0.x, f0.y, f1.x, f1.y);
}
__device__ __forceinline__ void st1(float* p, float v) { *p = v; }
__device__ __forceinline__ void st1(__half* p, float v) { *p = __float2half(v); }
__device__ __forceinline__ void addto(float* p, float v) { *p += v; }
__device__ __forceinline__ void addto(__half* p, float v) { *p = __float2half(__half2float(*p) + v); }
__device__ __forceinline__ void ld8(const float* p, float* o) {
  *(float4*)&o[0] = *(const float4*)&p[0];
  *(float4*)&o[4] = *(const float4*)&p[4];
}
__device__ __forceinline__ void ld8(const __half* p, float* o) {
  uint4 r = *(const uint4*)p;
  const __half2* h = reinterpret_cast<const __half2*>(&r);
#pragma unroll
  for (int i = 0; i < 4; ++i) { float2 f = __half22float2(h[i]); o[2*i] = f.x; o[2*i+1] = f.y; }
}

// ---------------------------------------------------------------------------
// persistent bidirectional GRU layer. MODE 0: layer0 (input x [64][2][1024],
// writes y0). MODE 1: layer1 (input y0, input-gate GEMM fused on the fly; no
// y1 materialization — instead accumulates Z=y1.Wq, U=y1.WoutA^T, c=y1.bq for
// the decoder, projecting the PREVIOUS step's h (already staged in LDS), with
// one extra epilogue step s=1024 for the lag).
// grid 256 WGs x 512 thr: WG = (dir d, 4-h-slice i0). Weights LDS-resident.
// One device-scope flag barrier per time step; h double-buffered in global.
// ---------------------------------------------------------------------------
template<int MODE, typename YT, typename ZT>
__global__ __launch_bounds__(512, 1)
void k_enc(const float* __restrict__ x0, const YT* __restrict__ yin,
           const float* __restrict__ Wih, const float* __restrict__ Whh,
           const float* __restrict__ bih, const float* __restrict__ bhh,
           YT* __restrict__ yout, float* __restrict__ hbuf,
           float* __restrict__ hfin, int* __restrict__ flags,
           int gen_base, int hfin_base,
           const float* __restrict__ Wq, const float* __restrict__ bq,
           const float* __restrict__ WoutA,
           ZT* __restrict__ Zp, float* __restrict__ Up, float* __restrict__ cp)
{
  constexpr int KTOT = MODE ? 1536 : 512;   // cols: [Whh 512 | Wih 1024]
  constexpr int NCH  = KTOT / 128;
  constexpr int PADW = KTOT + 4;
  constexpr int SMAX = MODE ? 1025 : 1024;  // +1 projection epilogue step
  __shared__ float Wl[12][PADW];            // 12 gate rows (r,z,n x 4 h-idx)
  __shared__ float Ast[64][132];            // staged A chunk [64 b][128 k]
  __shared__ float WqL[MODE ? 4 : 1][MODE ? 516 : 4];
  __shared__ float UL[MODE ? 516 : 4];
  __shared__ float bqL[MODE ? 516 : 4];

  const int g   = blockIdx.x;
  const int d   = g >> 7;                   // direction
  const int sl  = g & 127;                  // slice index
  const int i0  = sl * 4;
  const int tid = threadIdx.x;
  const int w   = tid >> 6, lane = tid & 63;
  const int b   = w*8 + (lane >> 3);        // batch owned by this thread
  const int il  = (lane >> 1) & 3;          // h-index within slice
  const int kh  = lane & 1;                 // k-split half (interleaved quads)
  const int i   = i0 + il;

  // stage weights once (resident across all steps)
  for (int u = tid; u < 12*KTOT; u += 512) {
    const int rr = u / KTOT, k = u - rr*KTOT;
    const int R  = (rr >> 2)*512 + i0 + (rr & 3);  // gate*512 + i
    float v;
    if (MODE == 0) v = Whh[(d*1536 + R)*512 + k];
    else v = (k < 512) ? Whh[(d*1536 + R)*512 + k]
                       : Wih[(size_t)(d*1536 + R)*1024 + (k - 512)];
    Wl[rr][k] = v;
  }
  if constexpr (MODE == 1) {
    for (int u = tid; u < 2048; u += 512) {
      const int il2 = u >> 9, k = u & 511;
      WqL[il2][k] = Wq[(d*512 + k)*512 + i0 + il2];  // Z[i] = sum_k y_k Wq[k_glob, i]
    }
    if (tid < 512) {
      UL[tid]  = WoutA[(size_t)sl*1536 + 512 + d*512 + tid];
      bqL[tid] = bq[d*512 + tid];
    }
  }
  __syncthreads();

  const int Rr = i, Rz = 512 + i, Rn = 1024 + i;
  const float biR = bih[d*1536 + Rr], biZ = bih[d*1536 + Rz], biN = bih[d*1536 + Rn];
  const float bhR = bhh[d*1536 + Rr], bhZ = bhh[d*1536 + Rz], bhN = bhh[d*1536 + Rn];
  float xwR0=0, xwR1=0, xwZ0=0, xwZ1=0, xwN0=0, xwN1=0;
  if (MODE == 0) {
    xwR0 = Wih[(d*1536 + Rr)*2 + 0]; xwR1 = Wih[(d*1536 + Rr)*2 + 1];
    xwZ0 = Wih[(d*1536 + Rz)*2 + 0]; xwZ1 = Wih[(d*1536 + Rz)*2 + 1];
    xwN0 = Wih[(d*1536 + Rn)*2 + 0]; xwN1 = Wih[(d*1536 + Rn)*2 + 1];
  }
  const float* wlR = Wl[0 + il];
  const float* wlZ = Wl[4 + il];
  const float* wlN = Wl[8 + il];
  const float* arow = Ast[b];

  for (int s = 0; s < SMAX; ++s) {
    // ---- wait: all WGs completed step s-1 ----
    if (tid < NWG) {
      int cnt = 0;
      while (__hip_atomic_load(&flags[tid*16], __ATOMIC_ACQUIRE,
                               __HIP_MEMORY_SCOPE_AGENT) < gen_base + s) {
        __builtin_amdgcn_s_sleep(2);
        if (++cnt > SPIN_MAX) break;  // deadlock parachute
      }
    }
    __syncthreads();
    __builtin_amdgcn_fence(__ATOMIC_ACQUIRE, "agent");

    const bool doG = (s < 1024);
    const int t = d ? (1023 - s) : s;             // only meaningful when doG
    const int cur = s & 1;
    const float* hsrc = hbuf + ((cur*2 + d)*64)*512;
    const int nch = doG ? NCH : 4;                // epilogue: h chunks only

    auto ldchunk = [&](int c, int r) -> float4 {
      const int idx = r*64 + lane, bl = idx >> 5, kq = idx & 31;
      const int bb = w*8 + bl;
      if (MODE == 0 || c < 4) return ld4(hsrc + bb*512 + c*128 + kq*4);
      return ld4(yin + ((size_t)bb*1024 + t)*1024 + (c-4)*128 + kq*4);
    };

    float aR = 0.f, aZ = 0.f, aNh = 0.f, aNi = 0.f, hold = 0.f;
    float zacc = 0.f, uacc = 0.f, cacc = 0.f;
    float4 nb[4];
#pragma unroll
    for (int r = 0; r < 4; ++r) nb[r] = ldchunk(0, r);

    for (int c = 0; c < nch; ++c) {
      // wave-private staging (each wave stages exactly the 8 b-rows it reads)
#pragma unroll
      for (int r = 0; r < 4; ++r) {
        const int idx = r*64 + lane, bl = idx >> 5, kq = idx & 31;
        *(float4*)&Ast[w*8 + bl][kq*4] = nb[r];
      }
      float4 pf[4] = {nb[0], nb[1], nb[2], nb[3]};
      if (c + 1 < nch) {
#pragma unroll
        for (int r = 0; r < 4; ++r) pf[r] = ldchunk(c+1, r);
      }
      const bool is_h = (MODE == 0) || (c < 4);
      const int cb = c*128;
      if (doG) {
        float accN = 0.f;
#pragma unroll
        for (int qq = 0; qq < 16; ++qq) {     // this thread: quads q ≡ kh (mod 2)
          const int kl = (qq*2 + kh)*4;
          const float4 hv = *(const float4*)(arow + kl);
          aR   += dot4(hv, *(const float4*)(wlR + cb + kl));
          aZ   += dot4(hv, *(const float4*)(wlZ + cb + kl));
          accN += dot4(hv, *(const float4*)(wlN + cb + kl));
        }
        if (is_h) aNh += accN; else aNi += accN;
        if (is_h && (i >> 7) == c) hold = arow[i & 127];
      }
      if constexpr (MODE == 1) {
        if (s >= 1 && c < 4) {                // project previous step's h (=y[t_prev])
          const float* wz = WqL[il];
#pragma unroll
          for (int qq = 0; qq < 16; ++qq) {
            const int kl = (qq*2 + kh)*4;
            zacc += dot4(*(const float4*)(arow + kl), *(const float4*)(wz + cb + kl));
          }
#pragma unroll
          for (int qq = 0; qq < 4; ++qq) {    // U/c: k split 8-ways (il,kh)
            const int kl = (qq*8 + il*2 + kh)*4;
            const float4 hv = *(const float4*)(arow + kl);
            uacc += dot4(hv, *(const float4*)(UL + cb + kl));
            if (sl == 0) cacc += dot4(hv, *(const float4*)(bqL + cb + kl));
          }
        }
      }
#pragma unroll
      for (int r = 0; r < 4; ++r) nb[r] = pf[r];
    }

    if (doG) {
      // combine the k-split halves (adjacent lanes)
      aR  += __shfl_xor(aR, 1);
      aZ  += __shfl_xor(aZ, 1);
      aNh += __shfl_xor(aNh, 1);
      if (MODE) aNi += __shfl_xor(aNi, 1);

      float NI;
      if (MODE == 0) {
        const float xa = x0[(b*2 + 0)*1024 + t];
        const float xb = x0[(b*2 + 1)*1024 + t];
        NI  = xa*xwN0 + xb*xwN1 + biN;
        aR += xa*xwR0 + xb*xwR1;
        aZ += xa*xwZ0 + xb*xwZ1;
      } else {
        NI = aNi + biN;
      }
      const float r_ = sigm(aR + biR + bhR);
      const float z_ = sigm(aZ + biZ + bhZ);
      const float n_ = tanhf(NI + r_*(aNh + bhN));
      const float hn = (1.f - z_)*n_ + z_*hold;

      if (kh == 0) {
        hbuf[(((cur^1)*2 + d)*64 + b)*512 + i] = hn;
        if constexpr (MODE == 0)
          st1(&yout[((size_t)b*1024 + t)*1024 + d*512 + i], hn);
        if (s == 1023) hfin[((hfin_base + d)*64 + b)*512 + i] = hn;
      }
    }
    if constexpr (MODE == 1) {
      if (s >= 1) {
        const int tp = d ? (1024 - s) : (s - 1);
        zacc += __shfl_xor(zacc, 1);
        uacc += __shfl_xor(uacc, 1); uacc += __shfl_xor(uacc, 2); uacc += __shfl_xor(uacc, 4);
        if (kh == 0) addto(&Zp[((size_t)b*1024 + tp)*512 + i], zacc);
        if ((lane & 7) == 0) addto(&Up[((size_t)b*1024 + tp)*128 + sl], uacc);
        if (sl == 0) {
          cacc += __shfl_xor(cacc, 1); cacc += __shfl_xor(cacc, 2); cacc += __shfl_xor(cacc, 4);
          if ((lane & 7) == 0) addto(&cp[b*1024 + tp], cacc);
        }
      }
    }
    // ---- arrive (not on the epilogue step) ----
    if (doG) {
      __syncthreads();
      if (tid == 0)
        __hip_atomic_store(&flags[g*16], gen_base + s + 1, __ATOMIC_RELEASE,
                           __HIP_MEMORY_SCOPE_AGENT);
    }
  }
}

// ---------------------------------------------------------------------------
// faithful torch h.view(B,-1) projection: hdec = hflat @ We2d.T + be2d
// h is (4,64,512); hflat is [64][2048]: hflat[b][c] = hfin[q>>6][q&63][c&511],
// q = b*4 + (c>>9).   We2d is [1024][2048] (K = 2048 — NOT 4096!).
// result[b][j] scatters to dech[0][b>>5][(2b + (j>>9))&63][j&511]
// ---------------------------------------------------------------------------
__global__ __launch_bounds__(256, 1)
void k_we2d(const float* __restrict__ hfin, const float* __restrict__ We2d,
            const float* __restrict__ be2d, float* __restrict__ dech,
            int* __restrict__ tok)
{
  const int g = blockIdx.x, tid = threadIdx.x;
  const int r = tid >> 2, jl = tid & 3;   // r = batch, j = output row
  const int j = g*4 + jl;
  const float* wr = We2d + (size_t)j*2048;
  float acc = 0.f;
  for (int c = 0; c < 2048; c += 4) {
    const int q = r*4 + (c >> 9);         // q < 256
    acc += dot4(*(const float4*)&hfin[((q >> 6)*64 + (q & 63))*512 + (c & 511)],
                *(const float4*)&wr[c]);
  }
  acc += be2d[j];
  const int lp = r >> 5, bb2 = 2*(r & 31) + (j >> 9), hh = j & 511;
  dech[(lp*64 + bb2)*512 + hh] = acc;   // parity 0
  if (g == 0 && tid < 64) tok[tid] = 0;
}

// ---------------------------------------------------------------------------
// persistent decoder: 32 steps x 4 barrier-phases
// A: cell l0, B: cell l1, D: attention over (Z,U,c) (all 256 WGs),
// E: combine + logits + argmax + outputs
// ---------------------------------------------------------------------------
template<typename ZT>
__global__ __launch_bounds__(256, 1)
void k_dec(const float* __restrict__ emb, const float* __restrict__ dWih,
           const float* __restrict__ dWhh, const float* __restrict__ dbih,
           const float* __restrict__ dbhh, const float* __restrict__ Wout,
           const float* __restrict__ bout, const ZT* __restrict__ Zp,
           const float* __restrict__ Up, const float* __restrict__ cp,
           float* __restrict__ dech, float* __restrict__ scor,
           float* __restrict__ pvU, float* __restrict__ pms,
           int* __restrict__ tok, int* __restrict__ flags,
           float* __restrict__ out, int gen_base)
{
  __shared__ float shmU[4][128];
  __shared__ float wms[8];
  __shared__ float shv[512];
  __shared__ float shl[128];

  const int g = blockIdx.x, tid = threadIdx.x;

  auto bwait = [&](int tgt) {
    if (tid < NWG) {
      int cnt = 0;
      while (__hip_atomic_load(&flags[tid*16], __ATOMIC_ACQUIRE,
                               __HIP_MEMORY_SCOPE_AGENT) < tgt) {
        __builtin_amdgcn_s_sleep(2);
        if (++cnt > SPIN_MAX) break;
      }
    }
    __syncthreads();
    __builtin_amdgcn_fence(__ATOMIC_ACQUIRE, "agent");
  };
  auto barr = [&](int tgt) {
    __syncthreads();
    if (tid == 0)
      __hip_atomic_store(&flags[g*16], tgt, __ATOMIC_RELEASE,
                         __HIP_MEMORY_SCOPE_AGENT);
  };

  for (int s = 0; s < 32; ++s) {
    const int p = s & 1, pn = p ^ 1;
    const int tb = gen_base + s*4;

    // ---- phase A: decoder cell, layer 0 ----
    bwait(tb);
    if (g < 64) {
      const int b = tid & 63, jj = tid >> 6;
      const float* xi = emb + tok[b]*512;
      const float* hh = dech + ((p*2 + 0)*64 + b)*512;
#pragma unroll
      for (int o = 0; o < 2; ++o) {
        const int j = g*8 + jj + o*4;
        const float* wi = dWih + j*512;
        const float* wh = dWhh + j*512;
        float acc = dbih[j] + dbhh[j];
        for (int k = 0; k < 512; k += 4) {
          acc += dot4(*(const float4*)&xi[k], *(const float4*)&wi[k]);
          acc += dot4(*(const float4*)&hh[k], *(const float4*)&wh[k]);
        }
        dech[((pn*2 + 0)*64 + b)*512 + j] = tanhf(acc);
      }
    }
    barr(tb+1);

    // ---- phase B: decoder cell, layer 1 ----
    bwait(tb+1);
    if (g < 64) {
      const int b = tid & 63, jj = tid >> 6;
      const float* xi = dech + ((pn*2 + 0)*64 + b)*512;
      const float* hh = dech + ((p*2 + 1)*64 + b)*512;
#pragma unroll
      for (int o = 0; o < 2; ++o) {
        const int j = g*8 + jj + o*4;
        const float* wi = dWih + (512 + j)*512;
        const float* wh = dWhh + (512 + j)*512;
        float acc = dbih[512 + j] + dbhh[512 + j];
        for (int k = 0; k < 512; k += 4) {
          acc += dot4(*(const float4*)&xi[k], *(const float4*)&wi[k]);
          acc += dot4(*(const float4*)&hh[k], *(const float4*)&wh[k]);
        }
        dech[((pn*2 + 1)*64 + b)*512 + j] = tanhf(acc);
      }
    }
    barr(tb+2);

    // ---- phase D: attention via Z.vec + c, accumulate U-weighted sums ----
    bwait(tb+2);
    {
      const int b = g >> 2, quarter = g & 3;
      const int w = tid >> 6, lane = tid & 63;
      const float* vecb = dech + ((pn*2 + 1)*64 + b)*512;
      float vr[8];
      *(float4*)&vr[0] = *(const float4*)&vecb[lane*8];
      *(float4*)&vr[4] = *(const float4*)&vecb[lane*8 + 4];
      float m = -INFINITY, ssum = 0.f, vu0 = 0.f, vu1 = 0.f;
      const int t0 = quarter*256 + w*64;
      for (int tg = 0; tg < 64; tg += 4) {   // 4-deep t-unroll for load depth
        float zz[4][8]; float cc[4]; float2 uu[4];
#pragma unroll
        for (int u = 0; u < 4; ++u) {
          const int t = t0 + tg + u;
          ld8(Zp + ((size_t)b*1024 + t)*512 + lane*8, zz[u]);
          uu[u] = *(const float2*)&Up[((size_t)b*1024 + t)*128 + lane*2];
          cc[u] = cp[b*1024 + t];
        }
#pragma unroll
        for (int u = 0; u < 4; ++u) {
          float sc = 0.f;
#pragma unroll
          for (int z = 0; z < 8; ++z) sc += zz[u][z]*vr[z];
#pragma unroll
          for (int off = 1; off < 64; off <<= 1) sc += __shfl_xor(sc, off);
          sc += cc[u];
          if (lane == 0) scor[b*1024 + t0 + tg + u] = sc;
          const float mn = fmaxf(m, sc);
          const float al = expf(m - mn);     // m=-inf first iter -> 0
          const float wt = expf(sc - mn);
          ssum = ssum*al + wt;
          vu0 = vu0*al + wt*uu[u].x;
          vu1 = vu1*al + wt*uu[u].y;
          m = mn;
        }
      }
      shmU[w][lane*2] = vu0; shmU[w][lane*2 + 1] = vu1;
      if (lane == 0) { wms[w] = m; wms[4 + w] = ssum; }
      __syncthreads();
      const float M = fmaxf(fmaxf(wms[0], wms[1]), fmaxf(wms[2], wms[3]));
      const float e0 = expf(wms[0]-M), e1 = expf(wms[1]-M),
                  e2 = expf(wms[2]-M), e3 = expf(wms[3]-M);
      const float S = e0*wms[4] + e1*wms[5] + e2*wms[6] + e3*wms[7];
      if (tid < 128)
        pvU[(b*4 + quarter)*128 + tid] =
            e0*shmU[0][tid] + e1*shmU[1][tid] + e2*shmU[2][tid] + e3*shmU[3][tid];
      if (tid == 0) { pms[(b*4+quarter)*2] = M; pms[(b*4+quarter)*2+1] = S; }
    }
    barr(tb+3);

    // ---- phase E: combine, logits, argmax, outputs ----
    bwait(tb+3);
    if (g < 64) {
      const int b = g;
      float Mc[4], Sc[4];
#pragma unroll
      for (int c = 0; c < 4; ++c) { Mc[c] = pms[(b*4+c)*2]; Sc[c] = pms[(b*4+c)*2+1]; }
      const float M = fmaxf(fmaxf(Mc[0],Mc[1]), fmaxf(Mc[2],Mc[3]));
      float ee[4]; float S = 0.f;
#pragma unroll
      for (int c = 0; c < 4; ++c) { ee[c] = expf(Mc[c]-M); S += ee[c]*Sc[c]; }
      const float invS = 1.f/S;
      const float* vecb = dech + ((pn*2 + 1)*64 + b)*512;
      shv[tid*2]   = vecb[tid*2];
      shv[tid*2+1] = vecb[tid*2+1];
      __syncthreads();
      if (tid < 128) {
        const float* wr = Wout + tid*1536;
        float acc = bout[tid];
        for (int k = 0; k < 512; k += 4)
          acc += dot4(*(const float4*)&shv[k], *(const float4*)&wr[k]);
        float att = 0.f;
#pragma unroll
        for (int c = 0; c < 4; ++c) att += ee[c]*pvU[(b*4 + c)*128 + tid];
        acc += att * invS;
        shl[tid] = acc;
        out[(b*32 + s)*128 + tid] = acc;              // vec_out
      }
      __syncthreads();
      if (tid == 0) {                                  // first-max argmax
        float best = shl[0]; int bi = 0;
        for (int j = 1; j < 128; ++j) if (shl[j] > best) { best = shl[j]; bi = j; }
        tok[b] = bi;
      }
      {
        const int t4 = tid*4;
#pragma unroll
        for (int u = 0; u < 4; ++u)
          out[327680 + (b*32 + s)*1024 + t4 + u] =
              expf(scor[b*1024 + t4 + u] - M)*invS;    // att_w
      }
      if (s == 31) {
        for (int u = tid; u < 1024; u += 256) {
          const int l = u >> 9, h = u & 511;
          out[262144 + (l*64 + b)*512 + h] = dech[((pn*2 + l)*64 + b)*512 + h];
        }
      }
    }
    barr(tb+4);
  }
}

// ---------------------------------------------------------------------------
template<typename YT, typename ZT>
static void run_all(void* const* d_in, void* d_out, void* d_ws, hipStream_t stream) {
  const float* x     = (const float*)d_in[0];
  const float* Wih0  = (const float*)d_in[1];
  const float* Whh0  = (const float*)d_in[2];
  const float* bih0  = (const float*)d_in[3];
  const float* bhh0  = (const float*)d_in[4];
  const float* Wih1  = (const float*)d_in[5];
  const float* Whh1  = (const float*)d_in[6];
  const float* bih1  = (const float*)d_in[7];
  const float* bhh1  = (const float*)d_in[8];
  const float* emb   = (const float*)d_in[9];
  const float* dWih  = (const float*)d_in[10];
  const float* dWhh  = (const float*)d_in[11];
  const float* dbih  = (const float*)d_in[12];
  const float* dbhh  = (const float*)d_in[13];
  const float* Wq    = (const float*)d_in[14];
  const float* bqv   = (const float*)d_in[15];
  const float* We2d  = (const float*)d_in[16];
  const float* be2d  = (const float*)d_in[17];
  const float* Wout  = (const float*)d_in[18];
  const float* boutv = (const float*)d_in[19];

  char* base = (char*)d_ws;
  size_t off = 0;
  auto carve = [&](size_t bytes) { size_t o = off; off += (bytes + 255) & ~(size_t)255; return o; };
  const size_t o_y0   = carve((size_t)67108864 * sizeof(YT));
  const size_t o_Z    = carve((size_t)33554432 * sizeof(ZT));
  const size_t o_U    = carve(33554432);   // 8388608 f
  const size_t o_c    = carve(262144);     // 65536 f
  const size_t o_hbuf = carve(1048576);    // 262144 f (2 layers x 2 buf x 2 dir x 64 x 512)
  const size_t o_flag = carve(16384);      // 256*16 int
  const size_t o_hfin = carve(524288);     // 4x64x512 f
  const size_t o_dech = carve(524288);     // 2x2x64x512 f
  const size_t o_scor = carve(262144);     // 64x1024 f
  const size_t o_pvU  = carve(131072);     // 256x128 f
  const size_t o_pms  = carve(2048);
  const size_t o_tok  = carve(256);

  YT*    y0    = (YT*)(base + o_y0);
  ZT*    Zp    = (ZT*)(base + o_Z);
  float* Up    = (float*)(base + o_U);
  float* cp    = (float*)(base + o_c);
  float* hbuf  = (float*)(base + o_hbuf);
  int*   flags = (int*)(base + o_flag);
  float* hfin  = (float*)(base + o_hfin);
  float* dech  = (float*)(base + o_dech);
  float* scor  = (float*)(base + o_scor);
  float* pvU   = (float*)(base + o_pvU);
  float* pms   = (float*)(base + o_pms);
  int*   tok   = (int*)(base + o_tok);

  // zero the accumulated/stateful span [Z .. flags] in one shot
  hipMemsetAsync(base + o_Z, 0, (o_flag + 16384) - o_Z, stream);

  k_enc<0, YT, ZT><<<256, 512, 0, stream>>>(
      x, (const YT*)nullptr, Wih0, Whh0, bih0, bhh0, y0, hbuf, hfin, flags,
      0, 0, nullptr, nullptr, nullptr, (ZT*)nullptr, nullptr, nullptr);
  k_enc<1, YT, ZT><<<256, 512, 0, stream>>>(
      nullptr, y0, Wih1, Whh1, bih1, bhh1, (YT*)nullptr, hbuf + 131072, hfin,
      flags, 1024, 2, Wq, bqv, Wout, Zp, Up, cp);
  k_we2d<<<256, 256, 0, stream>>>(hfin, We2d, be2d, dech, tok);
  k_dec<ZT><<<256, 256, 0, stream>>>(emb, dWih, dWhh, dbih, dbhh, Wout, boutv,
                                     Zp, Up, cp, dech, scor, pvU, pms, tok,
                                     flags, (float*)d_out, 2048);
}

extern "C" void kernel_launch(void* const* d_in, const int* in_sizes, int n_in,
                              void* d_out, int out_size, void* d_ws, size_t ws_size,
                              hipStream_t stream) {
  (void)in_sizes; (void)n_in;
  const size_t NEED_A = 438978816;   // all-fp32 tier
  const size_t NEED_B = 237652224;   // y0 fp16 + Z fp16 tier
  if (ws_size >= NEED_A) {
    run_all<float, float>(d_in, d_out, d_ws, stream);
  } else if (ws_size >= NEED_B) {
    run_all<__half, __half>(d_in, d_out, d_ws, stream);
  } else {
    // canary: ws too small for any tier — emit zeros (diagnosable, no fault)
    hipMemsetAsync(d_out, 0, (size_t)out_size * 4, stream);
  }
}

// Round 4
// 307960.425 us; speedup vs baseline: 1.2500x; 1.2500x over previous
//
#include <hip/hip_runtime.h>
#include <hip/hip_fp16.h>
#include <math.h>

#define GUARD_MAX (1<<20)

__device__ __forceinline__ float dot4(const float4 a, const float4 b) {
  return a.x*b.x + a.y*b.y + a.z*b.z + a.w*b.w;
}
__device__ __forceinline__ float sigm(float v) { return 1.f/(1.f + expf(-v)); }

__device__ __forceinline__ float4 ld4(const float* p) { return *(const float4*)p; }
__device__ __forceinline__ float4 ld4(const __half* p) {
  uint2 r = *(const uint2*)p;
  __half2 h0 = *reinterpret_cast<__half2*>(&r.x);
  __half2 h1 = *reinterpret_cast<__half2*>(&r.y);
  float2 f0 = __half22float2(h0), f1 = __half22float2(h1);
  return make_float4(f0.x, f0.y, f1.x, f1.y);
}
__device__ __forceinline__ void st1(float* p, float v) { *p = v; }
__device__ __forceinline__ void st1(__half* p, float v) { *p = __float2half(v); }
__device__ __forceinline__ void ld8(const float* p, float* o) {
  *(float4*)&o[0] = *(const float4*)&p[0];
  *(float4*)&o[4] = *(const float4*)&p[4];
}
__device__ __forceinline__ void ld8(const __half* p, float* o) {
  uint4 r = *(const uint4*)p;
  const __half2* h = reinterpret_cast<const __half2*>(&r);
#pragma unroll
  for (int i = 0; i < 4; ++i) { float2 f = __half22float2(h[i]); o[2*i] = f.x; o[2*i+1] = f.y; }
}

__device__ __forceinline__ void atomAddF(float* p, float v) {
  __hip_atomic_fetch_add(p, v, __ATOMIC_RELAXED, __HIP_MEMORY_SCOPE_AGENT);
}
// CAS-based packed-half add (compile-safe everywhere); p must be 4B-aligned
__device__ __forceinline__ void atomAddH2(__half* p, float lo, float hi) {
  unsigned int* u = (unsigned int*)p;
  unsigned int old = __hip_atomic_load(u, __ATOMIC_RELAXED, __HIP_MEMORY_SCOPE_AGENT);
  while (true) {
    __half2 h = *reinterpret_cast<__half2*>(&old);
    float2 f = __half22float2(h);
    __half2 nh = __floats2half2_rn(f.x + lo, f.y + hi);
    unsigned int nv = *reinterpret_cast<unsigned int*>(&nh);
    unsigned int got = atomicCAS(u, old, nv);
    if (got == old) break;
    old = got;
  }
}

// ---------------------------------------------------------------------------
// Flag barrier, storm-free version.
// wait: wave 0 scans `nscan` packed int flags with RELAXED agent loads (4 per
// lane), then ONE acquire fence (single buffer_inv), then __syncthreads.
// arrive: __syncthreads (drains all waves' stores into L2) + one RELEASE
// store (buffer_wbl2 publishes L2 to the coherence point).
// ---------------------------------------------------------------------------
__device__ __forceinline__ void bar_wait(const int* flags, int base, int nscan, int tgt) {
  const int tid = threadIdx.x;
  if (tid < 64) {
    const int* fp = flags + base + tid*4;
    const bool act = (tid*4) < nscan;
    int guard = 0;
    bool ok;
    do {
      int v0 = tgt, v1 = tgt, v2 = tgt, v3 = tgt;
      if (act) {
        v0 = __hip_atomic_load(fp+0, __ATOMIC_RELAXED, __HIP_MEMORY_SCOPE_AGENT);
        v1 = __hip_atomic_load(fp+1, __ATOMIC_RELAXED, __HIP_MEMORY_SCOPE_AGENT);
        v2 = __hip_atomic_load(fp+2, __ATOMIC_RELAXED, __HIP_MEMORY_SCOPE_AGENT);
        v3 = __hip_atomic_load(fp+3, __ATOMIC_RELAXED, __HIP_MEMORY_SCOPE_AGENT);
      }
      ok = (v0 >= tgt) && (v1 >= tgt) && (v2 >= tgt) && (v3 >= tgt);
      if (++guard > GUARD_MAX) break;   // deadlock parachute
    } while (!__all(ok));
    __builtin_amdgcn_fence(__ATOMIC_ACQUIRE, "agent");
  }
  __syncthreads();
}
__device__ __forceinline__ void bar_arrive(int* flags, int slot, int val) {
  __syncthreads();
  if (threadIdx.x == 0)
    __hip_atomic_store(&flags[slot], val, __ATOMIC_RELEASE, __HIP_MEMORY_SCOPE_AGENT);
}

// ---------------------------------------------------------------------------
// persistent bidirectional GRU layer. MODE 0: layer0 (input x [64][2][1024],
// writes y0). MODE 1: layer1 (input y0, input-gate GEMM fused on the fly; no
// y1 materialization — accumulates Z=y1.Wq, U=y1.WoutA^T, c=y1.bq via
// device-scope atomics, projecting the PREVIOUS step's h (staged in LDS),
// +1 epilogue step for the lag).
// grid 256 WGs x 512 thr: WG = (dir d, 4-h-slice). Weights LDS-resident.
// Per-DIRECTION flag barrier per step (128 WGs each); h double-buffered.
// enc flag slots: flags[0..255] (slot g), scan window [d*128, d*128+128).
// ---------------------------------------------------------------------------
template<int MODE, typename YT, typename ZT>
__global__ __launch_bounds__(512, 1)
void k_enc(const float* __restrict__ x0, const YT* __restrict__ yin,
           const float* __restrict__ Wih, const float* __restrict__ Whh,
           const float* __restrict__ bih, const float* __restrict__ bhh,
           YT* __restrict__ yout, float* __restrict__ hbuf,
           float* __restrict__ hfin, int* __restrict__ flags,
           int gen_base, int hfin_base,
           const float* __restrict__ Wq, const float* __restrict__ bq,
           const float* __restrict__ WoutA,
           ZT* __restrict__ Zp, float* __restrict__ Up, float* __restrict__ cp)
{
  constexpr int KTOT = MODE ? 1536 : 512;   // cols: [Whh 512 | Wih 1024]
  constexpr int NCH  = KTOT / 128;
  constexpr int PADW = KTOT + 4;
  constexpr int SMAX = MODE ? 1025 : 1024;  // +1 projection epilogue step
  __shared__ float Wl[12][PADW];            // 12 gate rows (r,z,n x 4 h-idx)
  __shared__ float Ast[64][132];            // staged A chunk [64 b][128 k]
  __shared__ float WqL[MODE ? 4 : 1][MODE ? 516 : 4];
  __shared__ float UL[MODE ? 516 : 4];
  __shared__ float bqL[MODE ? 516 : 4];

  const int g   = blockIdx.x;
  const int d   = g >> 7;                   // direction
  const int sl  = g & 127;                  // slice index
  const int i0  = sl * 4;
  const int tid = threadIdx.x;
  const int w   = tid >> 6, lane = tid & 63;
  const int b   = w*8 + (lane >> 3);        // batch owned by this thread
  const int il  = (lane >> 1) & 3;          // h-index within slice
  const int kh  = lane & 1;                 // k-split half (interleaved quads)
  const int i   = i0 + il;

  // stage weights once (resident across all steps)
  for (int u = tid; u < 12*KTOT; u += 512) {
    const int rr = u / KTOT, k = u - rr*KTOT;
    const int R  = (rr >> 2)*512 + i0 + (rr & 3);  // gate*512 + i
    float v;
    if (MODE == 0) v = Whh[(d*1536 + R)*512 + k];
    else v = (k < 512) ? Whh[(d*1536 + R)*512 + k]
                       : Wih[(size_t)(d*1536 + R)*1024 + (k - 512)];
    Wl[rr][k] = v;
  }
  if constexpr (MODE == 1) {
    for (int u = tid; u < 2048; u += 512) {
      const int il2 = u >> 9, k = u & 511;
      WqL[il2][k] = Wq[(d*512 + k)*512 + i0 + il2];  // Z[i] = sum_k y_k Wq[k_glob, i]
    }
    if (tid < 512) {
      UL[tid]  = WoutA[(size_t)sl*1536 + 512 + d*512 + tid];
      bqL[tid] = bq[d*512 + tid];
    }
  }
  __syncthreads();

  const int Rr = i, Rz = 512 + i, Rn = 1024 + i;
  const float biR = bih[d*1536 + Rr], biZ = bih[d*1536 + Rz], biN = bih[d*1536 + Rn];
  const float bhR = bhh[d*1536 + Rr], bhZ = bhh[d*1536 + Rz], bhN = bhh[d*1536 + Rn];
  float xwR0=0, xwR1=0, xwZ0=0, xwZ1=0, xwN0=0, xwN1=0;
  if (MODE == 0) {
    xwR0 = Wih[(d*1536 + Rr)*2 + 0]; xwR1 = Wih[(d*1536 + Rr)*2 + 1];
    xwZ0 = Wih[(d*1536 + Rz)*2 + 0]; xwZ1 = Wih[(d*1536 + Rz)*2 + 1];
    xwN0 = Wih[(d*1536 + Rn)*2 + 0]; xwN1 = Wih[(d*1536 + Rn)*2 + 1];
  }
  const float* wlR = Wl[0 + il];
  const float* wlZ = Wl[4 + il];
  const float* wlN = Wl[8 + il];
  const float* arow = Ast[b];

  for (int s = 0; s < SMAX; ++s) {
    // ---- wait: all same-direction WGs completed step s-1 ----
    bar_wait(flags, d*128, 128, gen_base + s);

    const bool doG = (s < 1024);
    const int t = d ? (1023 - s) : s;             // only meaningful when doG
    const int cur = s & 1;
    const float* hsrc = hbuf + ((cur*2 + d)*64)*512;
    const int nch = doG ? NCH : 4;                // epilogue: h chunks only

    auto ldchunk = [&](int c, int r) -> float4 {
      const int idx = r*64 + lane, bl = idx >> 5, kq = idx & 31;
      const int bb = w*8 + bl;
      if (MODE == 0 || c < 4) return ld4(hsrc + bb*512 + c*128 + kq*4);
      return ld4(yin + ((size_t)bb*1024 + t)*1024 + (c-4)*128 + kq*4);
    };

    float aR = 0.f, aZ = 0.f, aNh = 0.f, aNi = 0.f, hold = 0.f;
    float zacc = 0.f, uacc = 0.f, cacc = 0.f;
    float4 nb[4];
#pragma unroll
    for (int r = 0; r < 4; ++r) nb[r] = ldchunk(0, r);

    for (int c = 0; c < nch; ++c) {
      // wave-private staging (each wave stages exactly the 8 b-rows it reads)
#pragma unroll
      for (int r = 0; r < 4; ++r) {
        const int idx = r*64 + lane, bl = idx >> 5, kq = idx & 31;
        *(float4*)&Ast[w*8 + bl][kq*4] = nb[r];
      }
      float4 pf[4] = {nb[0], nb[1], nb[2], nb[3]};
      if (c + 1 < nch) {
#pragma unroll
        for (int r = 0; r < 4; ++r) pf[r] = ldchunk(c+1, r);
      }
      const bool is_h = (MODE == 0) || (c < 4);
      const int cb = c*128;
      if (doG) {
        float accN = 0.f;
#pragma unroll
        for (int qq = 0; qq < 16; ++qq) {     // this thread: quads q ≡ kh (mod 2)
          const int kl = (qq*2 + kh)*4;
          const float4 hv = *(const float4*)(arow + kl);
          aR   += dot4(hv, *(const float4*)(wlR + cb + kl));
          aZ   += dot4(hv, *(const float4*)(wlZ + cb + kl));
          accN += dot4(hv, *(const float4*)(wlN + cb + kl));
        }
        if (is_h) aNh += accN; else aNi += accN;
        if (is_h && (i >> 7) == c) hold = arow[i & 127];
      }
      if constexpr (MODE == 1) {
        if (s >= 1 && c < 4) {                // project previous step's h (=y[t_prev])
          const float* wz = WqL[il];
#pragma unroll
          for (int qq = 0; qq < 16; ++qq) {
            const int kl = (qq*2 + kh)*4;
            zacc += dot4(*(const float4*)(arow + kl), *(const float4*)(wz + cb + kl));
          }
#pragma unroll
          for (int qq = 0; qq < 4; ++qq) {    // U/c: k split 8-ways (il,kh)
            const int kl = (qq*8 + il*2 + kh)*4;
            const float4 hv = *(const float4*)(arow + kl);
            uacc += dot4(hv, *(const float4*)(UL + cb + kl));
            if (sl == 0) cacc += dot4(hv, *(const float4*)(bqL + cb + kl));
          }
        }
      }
#pragma unroll
      for (int r = 0; r < 4; ++r) nb[r] = pf[r];
    }

    if (doG) {
      // combine the k-split halves (adjacent lanes)
      aR  += __shfl_xor(aR, 1);
      aZ  += __shfl_xor(aZ, 1);
      aNh += __shfl_xor(aNh, 1);
      if (MODE) aNi += __shfl_xor(aNi, 1);

      float NI;
      if (MODE == 0) {
        const float xa = x0[(b*2 + 0)*1024 + t];
        const float xb = x0[(b*2 + 1)*1024 + t];
        NI  = xa*xwN0 + xb*xwN1 + biN;
        aR += xa*xwR0 + xb*xwR1;
        aZ += xa*xwZ0 + xb*xwZ1;
      } else {
        NI = aNi + biN;
      }
      const float r_ = sigm(aR + biR + bhR);
      const float z_ = sigm(aZ + biZ + bhZ);
      const float n_ = tanhf(NI + r_*(aNh + bhN));
      const float hn = (1.f - z_)*n_ + z_*hold;

      if (kh == 0) {
        hbuf[(((cur^1)*2 + d)*64 + b)*512 + i] = hn;
        if constexpr (MODE == 0)
          st1(&yout[((size_t)b*1024 + t)*1024 + d*512 + i], hn);
        if (s == 1023) hfin[((hfin_base + d)*64 + b)*512 + i] = hn;
      }
    }
    if constexpr (MODE == 1) {
      if (s >= 1) {
        const int tp = d ? (1024 - s) : (s - 1);
        zacc += __shfl_xor(zacc, 1);
        uacc += __shfl_xor(uacc, 1); uacc += __shfl_xor(uacc, 2); uacc += __shfl_xor(uacc, 4);
        const size_t zbase = ((size_t)b*1024 + tp)*512;
        if constexpr (sizeof(ZT) == 4) {
          if (kh == 0) atomAddF((float*)&Zp[zbase + i], zacc);
        } else {
          const float zhi = __shfl(zacc, lane + 2);   // partner il+1's value
          if (kh == 0 && (il & 1) == 0)
            atomAddH2((__half*)Zp + zbase + i, zacc, zhi);
        }
        if ((lane & 7) == 0) atomAddF(&Up[((size_t)b*1024 + tp)*128 + sl], uacc);
        if (sl == 0) {
          cacc += __shfl_xor(cacc, 1); cacc += __shfl_xor(cacc, 2); cacc += __shfl_xor(cacc, 4);
          if ((lane & 7) == 0) atomAddF(&cp[b*1024 + tp], cacc);
        }
      }
    }
    // ---- arrive (not on the epilogue step) ----
    if (doG) bar_arrive(flags, g, gen_base + s + 1);
  }
}

// ---------------------------------------------------------------------------
// faithful torch h.view(B,-1) projection: hdec = hflat @ We2d.T + be2d
// h is (4,64,512); hflat[b][c] = hfin[q>>6][q&63][c&511], q = b*4 + (c>>9).
// We2d is [1024][2048]. result res[r][j] reshapes (NL,B,H):
// flat = r*1024+j -> dech[0][r>>5][(2r + (j>>9)) & 63][j&511]   (verified r3)
// ---------------------------------------------------------------------------
__global__ __launch_bounds__(256, 1)
void k_we2d(const float* __restrict__ hfin, const float* __restrict__ We2d,
            const float* __restrict__ be2d, float* __restrict__ dech,
            int* __restrict__ tok)
{
  const int g = blockIdx.x, tid = threadIdx.x;
  const int r = tid >> 2, jl = tid & 3;   // r = batch row of hflat
  const int j = g*4 + jl;
  const float* wr = We2d + (size_t)j*2048;
  float acc = 0.f;
  for (int c = 0; c < 2048; c += 4) {
    const int q = r*4 + (c >> 9);         // q < 256
    acc += dot4(*(const float4*)&hfin[((q >> 6)*64 + (q & 63))*512 + (c & 511)],
                *(const float4*)&wr[c]);
  }
  acc += be2d[j];
  const int lp = r >> 5, bb2 = 2*(r & 31) + (j >> 9), hh = j & 511;
  dech[(lp*64 + bb2)*512 + hh] = acc;   // parity 0
  if (g == 0 && tid < 64) tok[tid] = 0;
}

// ---------------------------------------------------------------------------
// persistent decoder: 32 steps x 4 barrier-phases; flag slots flags[256..511]
// A: cell l0, B: cell l1, D: attention over (Z,U,c) (all 256 WGs),
// E: combine + logits + argmax + outputs
// ---------------------------------------------------------------------------
template<typename ZT>
__global__ __launch_bounds__(256, 1)
void k_dec(const float* __restrict__ emb, const float* __restrict__ dWih,
           const float* __restrict__ dWhh, const float* __restrict__ dbih,
           const float* __restrict__ dbhh, const float* __restrict__ Wout,
           const float* __restrict__ bout, const ZT* __restrict__ Zp,
           const float* __restrict__ Up, const float* __restrict__ cp,
           float* __restrict__ dech, float* __restrict__ scor,
           float* __restrict__ pvU, float* __restrict__ pms,
           int* __restrict__ tok, int* __restrict__ flags,
           float* __restrict__ out)
{
  __shared__ float shmU[4][128];
  __shared__ float wms[8];
  __shared__ float shv[512];
  __shared__ float shl[128];

  const int g = blockIdx.x, tid = threadIdx.x;

  for (int s = 0; s < 32; ++s) {
    const int p = s & 1, pn = p ^ 1;
    const int tb = s*4;

    // ---- phase A: decoder cell, layer 0 ----
    bar_wait(flags, 256, 256, tb);
    if (g < 64) {
      const int b = tid & 63, jj = tid >> 6;
      const float* xi = emb + tok[b]*512;
      const float* hh = dech + ((p*2 + 0)*64 + b)*512;
#pragma unroll
      for (int o = 0; o < 2; ++o) {
        const int j = g*8 + jj + o*4;
        const float* wi = dWih + j*512;
        const float* wh = dWhh + j*512;
        float acc = dbih[j] + dbhh[j];
        for (int k = 0; k < 512; k += 4) {
          acc += dot4(*(const float4*)&xi[k], *(const float4*)&wi[k]);
          acc += dot4(*(const float4*)&hh[k], *(const float4*)&wh[k]);
        }
        dech[((pn*2 + 0)*64 + b)*512 + j] = tanhf(acc);
      }
    }
    bar_arrive(flags, 256 + g, tb+1);

    // ---- phase B: decoder cell, layer 1 ----
    bar_wait(flags, 256, 256, tb+1);
    if (g < 64) {
      const int b = tid & 63, jj = tid >> 6;
      const float* xi = dech + ((pn*2 + 0)*64 + b)*512;
      const float* hh = dech + ((p*2 + 1)*64 + b)*512;
#pragma unroll
      for (int o = 0; o < 2; ++o) {
        const int j = g*8 + jj + o*4;
        const float* wi = dWih + (512 + j)*512;
        const float* wh = dWhh + (512 + j)*512;
        float acc = dbih[512 + j] + dbhh[512 + j];
        for (int k = 0; k < 512; k += 4) {
          acc += dot4(*(const float4*)&xi[k], *(const float4*)&wi[k]);
          acc += dot4(*(const float4*)&hh[k], *(const float4*)&wh[k]);
        }
        dech[((pn*2 + 1)*64 + b)*512 + j] = tanhf(acc);
      }
    }
    bar_arrive(flags, 256 + g, tb+2);

    // ---- phase D: attention via Z.vec + c, accumulate U-weighted sums ----
    bar_wait(flags, 256, 256, tb+2);
    {
      const int b = g >> 2, quarter = g & 3;
      const int w = tid >> 6, lane = tid & 63;
      const float* vecb = dech + ((pn*2 + 1)*64 + b)*512;
      float vr[8];
      *(float4*)&vr[0] = *(const float4*)&vecb[lane*8];
      *(float4*)&vr[4] = *(const float4*)&vecb[lane*8 + 4];
      float m = -INFINITY, ssum = 0.f, vu0 = 0.f, vu1 = 0.f;
      const int t0 = quarter*256 + w*64;
      for (int tg = 0; tg < 64; tg += 4) {   // 4-deep t-unroll for load depth
        float zz[4][8]; float cc[4]; float2 uu[4];
#pragma unroll
        for (int u = 0; u < 4; ++u) {
          const int t = t0 + tg + u;
          ld8(Zp + ((size_t)b*1024 + t)*512 + lane*8, zz[u]);
          uu[u] = *(const float2*)&Up[((size_t)b*1024 + t)*128 + lane*2];
          cc[u] = cp[b*1024 + t];
        }
#pragma unroll
        for (int u = 0; u < 4; ++u) {
          float sc = 0.f;
#pragma unroll
          for (int z = 0; z < 8; ++z) sc += zz[u][z]*vr[z];
#pragma unroll
          for (int off = 1; off < 64; off <<= 1) sc += __shfl_xor(sc, off);
          sc += cc[u];
          if (lane == 0) scor[b*1024 + t0 + tg + u] = sc;
          const float mn = fmaxf(m, sc);
          const float al = expf(m - mn);     // m=-inf first iter -> 0
          const float wt = expf(sc - mn);
          ssum = ssum*al + wt;
          vu0 = vu0*al + wt*uu[u].x;
          vu1 = vu1*al + wt*uu[u].y;
          m = mn;
        }
      }
      shmU[w][lane*2] = vu0; shmU[w][lane*2 + 1] = vu1;
      if (lane == 0) { wms[w] = m; wms[4 + w] = ssum; }
      __syncthreads();
      const float M = fmaxf(fmaxf(wms[0], wms[1]), fmaxf(wms[2], wms[3]));
      const float e0 = expf(wms[0]-M), e1 = expf(wms[1]-M),
                  e2 = expf(wms[2]-M), e3 = expf(wms[3]-M);
      const float S = e0*wms[4] + e1*wms[5] + e2*wms[6] + e3*wms[7];
      if (tid < 128)
        pvU[(b*4 + quarter)*128 + tid] =
            e0*shmU[0][tid] + e1*shmU[1][tid] + e2*shmU[2][tid] + e3*shmU[3][tid];
      if (tid == 0) { pms[(b*4+quarter)*2] = M; pms[(b*4+quarter)*2+1] = S; }
      (void)S;
    }
    bar_arrive(flags, 256 + g, tb+3);

    // ---- phase E: combine, logits, argmax, outputs ----
    bar_wait(flags, 256, 256, tb+3);
    if (g < 64) {
      const int b = g;
      float Mc[4], Sc[4];
#pragma unroll
      for (int c = 0; c < 4; ++c) { Mc[c] = pms[(b*4+c)*2]; Sc[c] = pms[(b*4+c)*2+1]; }
      const float M = fmaxf(fmaxf(Mc[0],Mc[1]), fmaxf(Mc[2],Mc[3]));
      float ee[4]; float S = 0.f;
#pragma unroll
      for (int c = 0; c < 4; ++c) { ee[c] = expf(Mc[c]-M); S += ee[c]*Sc[c]; }
      const float invS = 1.f/S;
      const float* vecb = dech + ((pn*2 + 1)*64 + b)*512;
      shv[tid*2]   = vecb[tid*2];
      shv[tid*2+1] = vecb[tid*2+1];
      __syncthreads();
      if (tid < 128) {
        const float* wr = Wout + tid*1536;
        float acc = bout[tid];
        for (int k = 0; k < 512; k += 4)
          acc += dot4(*(const float4*)&shv[k], *(const float4*)&wr[k]);
        float att = 0.f;
#pragma unroll
        for (int c = 0; c < 4; ++c) att += ee[c]*pvU[(b*4 + c)*128 + tid];
        acc += att * invS;
        shl[tid] = acc;
        out[(b*32 + s)*128 + tid] = acc;              // vec_out
      }
      __syncthreads();
      if (tid == 0) {                                  // first-max argmax
        float best = shl[0]; int bi = 0;
        for (int j = 1; j < 128; ++j) if (shl[j] > best) { best = shl[j]; bi = j; }
        tok[b] = bi;
      }
      {
        const int t4 = tid*4;
#pragma unroll
        for (int u = 0; u < 4; ++u)
          out[327680 + (b*32 + s)*1024 + t4 + u] =
              expf(scor[b*1024 + t4 + u] - M)*invS;    // att_w
      }
      if (s == 31) {
        for (int u = tid; u < 1024; u += 256) {
          const int l = u >> 9, h = u & 511;
          out[262144 + (l*64 + b)*512 + h] = dech[((pn*2 + l)*64 + b)*512 + h];
        }
      }
    }
    bar_arrive(flags, 256 + g, tb+4);
  }
}

// ---------------------------------------------------------------------------
template<typename YT, typename ZT>
static void run_all(void* const* d_in, void* d_out, void* d_ws, hipStream_t stream) {
  const float* x     = (const float*)d_in[0];
  const float* Wih0  = (const float*)d_in[1];
  const float* Whh0  = (const float*)d_in[2];
  const float* bih0  = (const float*)d_in[3];
  const float* bhh0  = (const float*)d_in[4];
  const float* Wih1  = (const float*)d_in[5];
  const float* Whh1  = (const float*)d_in[6];
  const float* bih1  = (const float*)d_in[7];
  const float* bhh1  = (const float*)d_in[8];
  const float* emb   = (const float*)d_in[9];
  const float* dWih  = (const float*)d_in[10];
  const float* dWhh  = (const float*)d_in[11];
  const float* dbih  = (const float*)d_in[12];
  const float* dbhh  = (const float*)d_in[13];
  const float* Wq    = (const float*)d_in[14];
  const float* bqv   = (const float*)d_in[15];
  const float* We2d  = (const float*)d_in[16];
  const float* be2d  = (const float*)d_in[17];
  const float* Wout  = (const float*)d_in[18];
  const float* boutv = (const float*)d_in[19];

  char* base = (char*)d_ws;
  size_t off = 0;
  auto carve = [&](size_t bytes) { size_t o = off; off += (bytes + 255) & ~(size_t)255; return o; };
  const size_t o_y0   = carve((size_t)67108864 * sizeof(YT));
  const size_t o_Z    = carve((size_t)33554432 * sizeof(ZT));
  const size_t o_U    = carve(33554432);   // 8388608 f
  const size_t o_c    = carve(262144);     // 65536 f
  const size_t o_hbuf = carve(1048576);    // 262144 f (2 layers x 2 buf x 2 dir x 64 x 512)
  const size_t o_flag = carve(16384);      // enc flags [0..255], dec flags [256..511]
  const size_t o_hfin = carve(524288);     // 4x64x512 f
  const size_t o_dech = carve(524288);     // 2x2x64x512 f
  const size_t o_scor = carve(262144);     // 64x1024 f
  const size_t o_pvU  = carve(131072);     // 256x128 f
  const size_t o_pms  = carve(2048);
  const size_t o_tok  = carve(256);

  YT*    y0    = (YT*)(base + o_y0);
  ZT*    Zp    = (ZT*)(base + o_Z);
  float* Up    = (float*)(base + o_U);
  float* cp    = (float*)(base + o_c);
  float* hbuf  = (float*)(base + o_hbuf);
  int*   flags = (int*)(base + o_flag);
  float* hfin  = (float*)(base + o_hfin);
  float* dech  = (float*)(base + o_dech);
  float* scor  = (float*)(base + o_scor);
  float* pvU   = (float*)(base + o_pvU);
  float* pms   = (float*)(base + o_pms);
  int*   tok   = (int*)(base + o_tok);

  // zero the accumulated/stateful span [Z .. flags] in one shot
  hipMemsetAsync(base + o_Z, 0, (o_flag + 16384) - o_Z, stream);

  k_enc<0, YT, ZT><<<256, 512, 0, stream>>>(
      x, (const YT*)nullptr, Wih0, Whh0, bih0, bhh0, y0, hbuf, hfin, flags,
      0, 0, nullptr, nullptr, nullptr, (ZT*)nullptr, nullptr, nullptr);
  k_enc<1, YT, ZT><<<256, 512, 0, stream>>>(
      nullptr, y0, Wih1, Whh1, bih1, bhh1, (YT*)nullptr, hbuf + 131072, hfin,
      flags, 1024, 2, Wq, bqv, Wout, Zp, Up, cp);
  k_we2d<<<256, 256, 0, stream>>>(hfin, We2d, be2d, dech, tok);
  k_dec<ZT><<<256, 256, 0, stream>>>(emb, dWih, dWhh, dbih, dbhh, Wout, boutv,
                                     Zp, Up, cp, dech, scor, pvU, pms, tok,
                                     flags, (float*)d_out);
}

extern "C" void kernel_launch(void* const* d_in, const int* in_sizes, int n_in,
                              void* d_out, int out_size, void* d_ws, size_t ws_size,
                              hipStream_t stream) {
  (void)in_sizes; (void)n_in;
  const size_t NEED_A = 438978816;   // y0 f32, Z f32
  const size_t NEED_B = 304761088;   // y0 f16, Z f32
  const size_t NEED_C = 237652224;   // y0 f16, Z f16 (CAS half2 atomics)
  if (ws_size >= NEED_A) {
    run_all<float, float>(d_in, d_out, d_ws, stream);
  } else if (ws_size >= NEED_B) {
    run_all<__half, float>(d_in, d_out, d_ws, stream);
  } else if (ws_size >= NEED_C) {
    run_all<__half, __half>(d_in, d_out, d_ws, stream);
  } else {
    // canary: ws too small for any tier — emit zeros (diagnosable, no fault)
    hipMemsetAsync(d_out, 0, (size_t)out_size * 4, stream);
  }
}